// Round 10
// baseline (203.758 us; speedup 1.0000x reference)
//
#include <hip/hip_runtime.h>

// stimuli [4,32,304,608,1] fp32, eye [4,32,2,3] fp32
#define BH 304
#define BW 608
#define BHW (BH * BW)     // 184832 = 512 * 361
#define NFRAMES 128

typedef float vf2 __attribute__((ext_vector_type(2)));
typedef float vf4 __attribute__((ext_vector_type(4)));

// 256 threads/block, block covers 512 consecutive px (<=2 image rows).
// Fast path (|dx/px|<1.98 && |dy/px|<0.999, ~91% of frames): each thread does an
// adjacent pixel PAIR via 3 dwordx4 row gathers + 1 dwordx2 store (2 addr/px).
// Slow path: proven per-pixel dwordx2 scheme (3 addr/px).
__global__ __launch_bounds__(256) void warp_bilinear_pair_kernel(
    const float* __restrict__ stimuli,
    const float* __restrict__ eye,
    float* __restrict__ out)
{
    const int n    = blockIdx.y;            // frame (wave-uniform)
    const int base = blockIdx.x * 512;      // block's first pixel (uniform)
    const int py0  = base / BW;             // uniform -> SALU
    const int pc0  = base - py0 * BW;       // even

    const float* aff = eye + n * 6;
    const float a00 = aff[0], a01 = aff[1], a02 = aff[2];
    const float a10 = aff[3], a11 = aff[4], a12 = aff[5];

    const float yyr0 = -1.0f + 2.0f * (float)py0       / (float)(BH - 1);
    const float yyr1 = -1.0f + 2.0f * (float)(py0 + 1) / (float)(BH - 1);
    const float a01yy0 = a01 * yyr0, a01yy1 = a01 * yyr1;
    const float a11yy0 = a11 * yyr0, a11yy1 = a11 * yyr1;

    // source-coordinate step per +1 output px (frame-uniform)
    const float dxpp = a00 * (float)BW / (float)(BW - 1);
    const float dypp = a10 * (float)BH / (float)(BW - 1);

    const float* __restrict__ img = stimuli + (size_t)n * BHW;
    const bool fast = (fabsf(dxpp) < 1.98f) && (fabsf(dypp) < 0.999f);

    if (fast) {
        const int off  = pc0 + 2 * (int)threadIdx.x;   // even; pair never straddles a row
        const bool wrap = off >= BW;
        const int px   = wrap ? off - BW : off;
        const float a01yy = wrap ? a01yy1 : a01yy0;
        const float a11yy = wrap ? a11yy1 : a11yy0;

        // even pixel: formula textually identical to prior passing rounds
        const float xx = -1.0f + 2.0f * (float)px / (float)(BW - 1);
        const float xe = (a00 * xx + a01yy + a02 + 1.0f) * (0.5f * (float)BW);
        const float ye = (a10 * xx + a11yy + a12 + 1.0f) * (0.5f * (float)BH);
        const float xo = xe + dxpp;      // odd pixel via uniform delta
        const float yo = ye + dypp;

        const float xef = floorf(xe), xof = floorf(xo);
        const float yef = floorf(ye), yof = floorf(yo);
        const int x0e = (int)xef, x0o = (int)xof;
        const int y0e = (int)yef, y0o = (int)yof;

        // 4-col x 3-row window covering both pixels' 2x2 taps (interior-exact)
        const int xm = min(x0e, x0o);
        const int ym = min(y0e, y0o);
        const int xp = min(max(xm, 0), BW - 4);
        const int yp = min(max(ym, 0), BH - 3);

        const float* rowp = img + yp * BW + xp;
        vf4 r0, r1, r2;
        __builtin_memcpy(&r0, rowp, 16);
        __builtin_memcpy(&r1, rowp + BW, 16);
        __builtin_memcpy(&r2, rowp + 2 * BW, 16);

        float res2[2];
        #pragma unroll
        for (int k = 0; k < 2; ++k) {
            const float x   = k ? xo  : xe;
            const float y   = k ? yo  : ye;
            const float x0f = k ? xof : xef;
            const float y0f = k ? yof : yef;
            const int   x0  = k ? x0o : x0e;
            const int   y0  = k ? y0o : y0e;

            const int dx = x0 - xp;     // 0..2 for interior px
            const int dy = y0 - yp;     // 0..1 for interior px
            const vf4 ra = (dy >= 1) ? r1 : r0;
            const vf4 rb = (dy >= 1) ? r2 : r1;
            const float Ia = (dx >= 1) ? ((dx >= 2) ? ra.z : ra.y) : ra.x;
            const float Ic = (dx >= 1) ? ((dx >= 2) ? ra.w : ra.z) : ra.y;
            const float Ib = (dx >= 1) ? ((dx >= 2) ? rb.z : rb.y) : rb.x;
            const float Id = (dx >= 1) ? ((dx >= 2) ? rb.w : rb.z) : rb.y;

            const float fx = x - x0f;
            const float fy = y - y0f;
            const float ix0 = Ia + fx * (Ic - Ia);
            const float ix1 = Ib + fx * (Id - Ib);
            const float r = ix0 + fy * (ix1 - ix0);
            const bool ok = ((unsigned)x0 < (unsigned)(BW - 1)) &&
                            ((unsigned)y0 < (unsigned)(BH - 1));
            res2[k] = ok ? r : 0.0f;
        }

        vf2 res; res.x = res2[0]; res.y = res2[1];
        __builtin_memcpy(out + (size_t)n * BHW + base + 2 * (int)threadIdx.x, &res, 8);
    } else {
        // slow path: 2 px/thread at stride 256 (round-7 proven structure)
        #pragma unroll
        for (int k = 0; k < 2; ++k) {
            const int off2 = pc0 + (int)threadIdx.x + k * 256;
            const bool w2  = off2 >= BW;
            const int px2  = w2 ? off2 - BW : off2;
            const float a01y = w2 ? a01yy1 : a01yy0;
            const float a11y = w2 ? a11yy1 : a11yy0;

            const float xx2 = -1.0f + 2.0f * (float)px2 / (float)(BW - 1);
            const float x = (a00 * xx2 + a01y + a02 + 1.0f) * (0.5f * (float)BW);
            const float y = (a10 * xx2 + a11y + a12 + 1.0f) * (0.5f * (float)BH);

            const float x0f = floorf(x), y0f = floorf(y);
            const int x0 = (int)x0f, y0 = (int)y0f;
            const int xq = min(max(x0, 0), BW - 2);
            const int yq = min(max(y0, 0), BH - 2);

            const float* rp = img + yq * BW + xq;
            vf2 va, vb;
            __builtin_memcpy(&va, rp, 8);
            __builtin_memcpy(&vb, rp + BW, 8);

            const float fx = x - x0f, fy = y - y0f;
            const bool ok = ((unsigned)x0 < (unsigned)(BW - 1)) &&
                            ((unsigned)y0 < (unsigned)(BH - 1));
            const float ix0 = va.x + fx * (va.y - va.x);
            const float ix1 = vb.x + fx * (vb.y - vb.x);
            const float r = ix0 + fy * (ix1 - ix0);
            out[(size_t)n * BHW + base + (int)threadIdx.x + k * 256] = ok ? r : 0.0f;
        }
    }
}

extern "C" void kernel_launch(void* const* d_in, const int* in_sizes, int n_in,
                              void* d_out, int out_size, void* d_ws, size_t ws_size,
                              hipStream_t stream) {
    const float* stimuli = (const float*)d_in[0];
    const float* eye     = (const float*)d_in[1];
    float* out = (float*)d_out;

    dim3 grid(BHW / 512, NFRAMES);   // 361 x 128
    dim3 block(256);
    warp_bilinear_pair_kernel<<<grid, block, 0, stream>>>(stimuli, eye, out);
}

// Round 12
// 193.045 us; speedup vs baseline: 1.0555x; 1.0555x over previous
//
#include <hip/hip_runtime.h>

// stimuli [4,32,304,608,1] fp32, eye [4,32,2,3] fp32
#define BH 304
#define BW 608
#define BHW (BH * BW)     // 184832 = 512 * 361
#define NFRAMES 128

typedef float vf2 __attribute__((ext_vector_type(2)));

// 128 threads/block, 4 px/thread at stride 128 (R6's proven memory shape:
// lane-consecutive gathers, 8 dwordx2 loads in flight, coalesced dword stores).
// Per-pixel math collapsed to 1 cvt + 2 FMA via block-uniform affine hoisting:
//   x = Ax*px + Bx(row),  Ax/Bx computed once per block in fp64.
__global__ __launch_bounds__(128) void warp_bilinear_fma_kernel(
    const float* __restrict__ stimuli,
    const float* __restrict__ eye,
    float* __restrict__ out)
{
    const int n    = blockIdx.y;            // frame (wave-uniform)
    const int base = blockIdx.x * 512;      // block's first pixel (uniform)
    const int py0  = base / BW;             // uniform -> SALU
    const int pc0  = base - py0 * BW;

    // Uniform fp64 setup (negligible cost, high accuracy):
    // x = (a00*xx + a01*yy + a02 + 1)*(W/2), xx = -1 + 2*px/(W-1)
    //   = Ax*px + Bx,  Ax = a00*(2/(W-1))*(W/2),  Bx = (a01*yy + a02 + 1 - a00)*(W/2)
    const float* aff = eye + n * 6;
    const double a00 = aff[0], a01 = aff[1], a02 = aff[2];
    const double a10 = aff[3], a11 = aff[4], a12 = aff[5];

    const double yy0 = -1.0 + 2.0 * (double)py0       / (double)(BH - 1);
    const double yy1 = -1.0 + 2.0 * (double)(py0 + 1) / (double)(BH - 1);

    const float Ax  = (float)(a00 * (2.0 / (double)(BW - 1)) * (0.5 * (double)BW));
    const float Ay  = (float)(a10 * (2.0 / (double)(BW - 1)) * (0.5 * (double)BH));
    const float Bx0 = (float)((a01 * yy0 + a02 + 1.0 - a00) * (0.5 * (double)BW));
    const float Bx1 = (float)((a01 * yy1 + a02 + 1.0 - a00) * (0.5 * (double)BW));
    const float By0 = (float)((a11 * yy0 + a12 + 1.0 - a10) * (0.5 * (double)BH));
    const float By1 = (float)((a11 * yy1 + a12 + 1.0 - a10) * (0.5 * (double)BH));

    const float* __restrict__ img = stimuli + (size_t)n * BHW;

    float fxs[4], fys[4];
    bool  ok[4];
    vf2   vA[4], vB[4];

    // Phase 1: 2 FMA coords + issue all 8 dwordx2 gathers
    #pragma unroll
    for (int k = 0; k < 4; ++k) {
        const int off  = pc0 + (int)threadIdx.x + k * 128;   // < 2*BW
        const bool wrap = (off >= BW);
        const float pxf = (float)(wrap ? off - BW : off);

        const float x = fmaf(Ax, pxf, wrap ? Bx1 : Bx0);
        const float y = fmaf(Ay, pxf, wrap ? By1 : By0);

        const float x0f = floorf(x);
        const float y0f = floorf(y);
        const int x0 = (int)x0f;
        const int y0 = (int)y0f;

        fxs[k] = x - x0f;
        fys[k] = y - y0f;
        ok[k] = ((unsigned)x0 < (unsigned)(BW - 1)) & ((unsigned)y0 < (unsigned)(BH - 1));

        const int xq = min(max(x0, 0), BW - 2);   // med3
        const int yq = min(max(y0, 0), BH - 2);

        const float* rp = img + yq * BW + xq;
        __builtin_memcpy(&vA[k], rp, 8);          // row y0: [x0, x0+1]
        __builtin_memcpy(&vB[k], rp + BW, 8);     // row y0+1: same addr + imm offset
    }

    // Phase 2: factored lerp + zero-mask, coalesced dword stores
    #pragma unroll
    for (int k = 0; k < 4; ++k) {
        const float fx = fxs[k], fy = fys[k];
        const float ix0 = vA[k].x + fx * (vA[k].y - vA[k].x);
        const float ix1 = vB[k].x + fx * (vB[k].y - vB[k].x);
        float r = ix0 + fy * (ix1 - ix0);
        r = ok[k] ? r : 0.0f;
        out[(size_t)n * BHW + base + (int)threadIdx.x + k * 128] = r;
    }
}

extern "C" void kernel_launch(void* const* d_in, const int* in_sizes, int n_in,
                              void* d_out, int out_size, void* d_ws, size_t ws_size,
                              hipStream_t stream) {
    const float* stimuli = (const float*)d_in[0];
    const float* eye     = (const float*)d_in[1];
    float* out = (float*)d_out;

    dim3 grid(BHW / 512, NFRAMES);   // 361 x 128
    dim3 block(128);
    warp_bilinear_fma_kernel<<<grid, block, 0, stream>>>(stimuli, eye, out);
}

// Round 16
// 179.257 us; speedup vs baseline: 1.1367x; 1.0769x over previous
//
#include <hip/hip_runtime.h>

// stimuli [4,32,304,608,1] fp32, eye [4,32,2,3] fp32
#define BH 304
#define BW 608
#define BHW (BH * BW)     // 184832 = 512 * 361
#define NFRAMES 128

typedef float vf2 __attribute__((ext_vector_type(2)));

// R12 structure (128 thr/block, 4 px/thread stride-128, lane-consecutive dwordx2
// gathers, block-uniform fp64-hoisted 2-FMA coords) + NEW: gathers are
// exec-masked by the validity test. ~69% of pixels are exactly 0 (clamp
// cancellation) and skip both loads; whole-dead waves skip via execz.
__global__ __launch_bounds__(128) void warp_bilinear_mask_kernel(
    const float* __restrict__ stimuli,
    const float* __restrict__ eye,
    float* __restrict__ out)
{
    const int n    = blockIdx.y;            // frame (wave-uniform)
    const int base = blockIdx.x * 512;      // block's first pixel (uniform)
    const int py0  = base / BW;             // uniform -> SALU
    const int pc0  = base - py0 * BW;

    const float* aff = eye + n * 6;
    const double a00 = aff[0], a01 = aff[1], a02 = aff[2];
    const double a10 = aff[3], a11 = aff[4], a12 = aff[5];

    const double yy0 = -1.0 + 2.0 * (double)py0       / (double)(BH - 1);
    const double yy1 = -1.0 + 2.0 * (double)(py0 + 1) / (double)(BH - 1);

    const float Ax  = (float)(a00 * (2.0 / (double)(BW - 1)) * (0.5 * (double)BW));
    const float Ay  = (float)(a10 * (2.0 / (double)(BW - 1)) * (0.5 * (double)BH));
    const float Bx0 = (float)((a01 * yy0 + a02 + 1.0 - a00) * (0.5 * (double)BW));
    const float Bx1 = (float)((a01 * yy1 + a02 + 1.0 - a00) * (0.5 * (double)BW));
    const float By0 = (float)((a11 * yy0 + a12 + 1.0 - a10) * (0.5 * (double)BH));
    const float By1 = (float)((a11 * yy1 + a12 + 1.0 - a10) * (0.5 * (double)BH));

    const float* __restrict__ img = stimuli + (size_t)n * BHW;

    float fxs[4], fys[4];
    bool  ok[4];
    vf2   vA[4], vB[4];

    // Phase 1: 2-FMA coords; gathers only for valid lanes (exec-masked)
    #pragma unroll
    for (int k = 0; k < 4; ++k) {
        const int off  = pc0 + (int)threadIdx.x + k * 128;   // < 2*BW
        const bool wrap = (off >= BW);
        const float pxf = (float)(wrap ? off - BW : off);

        const float x = fmaf(Ax, pxf, wrap ? Bx1 : Bx0);
        const float y = fmaf(Ay, pxf, wrap ? By1 : By0);

        const float x0f = floorf(x);
        const float y0f = floorf(y);
        const int x0 = (int)x0f;
        const int y0 = (int)y0f;

        fxs[k] = x - x0f;
        fys[k] = y - y0f;
        const bool v = ((unsigned)x0 < (unsigned)(BW - 1)) &
                       ((unsigned)y0 < (unsigned)(BH - 1));
        ok[k] = v;

        vA[k] = (vf2)0.0f;
        vB[k] = (vf2)0.0f;
        if (v) {
            // in-bounds by construction: x0 in [0,606], y0 in [0,302]
            const float* rp = img + y0 * BW + x0;
            __builtin_memcpy(&vA[k], rp, 8);          // row y0: [x0, x0+1]
            __builtin_memcpy(&vB[k], rp + BW, 8);     // row y0+1, same addr + imm
        }
    }

    // Phase 2: factored lerp + zero-mask, coalesced dword stores
    #pragma unroll
    for (int k = 0; k < 4; ++k) {
        const float fx = fxs[k], fy = fys[k];
        const float ix0 = vA[k].x + fx * (vA[k].y - vA[k].x);
        const float ix1 = vB[k].x + fx * (vB[k].y - vB[k].x);
        float r = ix0 + fy * (ix1 - ix0);
        r = ok[k] ? r : 0.0f;
        out[(size_t)n * BHW + base + (int)threadIdx.x + k * 128] = r;
    }
}

extern "C" void kernel_launch(void* const* d_in, const int* in_sizes, int n_in,
                              void* d_out, int out_size, void* d_ws, size_t ws_size,
                              hipStream_t stream) {
    const float* stimuli = (const float*)d_in[0];
    const float* eye     = (const float*)d_in[1];
    float* out = (float*)d_out;

    dim3 grid(BHW / 512, NFRAMES);   // 361 x 128
    dim3 block(128);
    warp_bilinear_mask_kernel<<<grid, block, 0, stream>>>(stimuli, eye, out);
}